// Round 11
// baseline (238.824 us; speedup 1.0000x reference)
//
#include <hip/hip_runtime.h>
#include <hip/hip_bf16.h>

// GCN 2-layer: N=50000 nodes, E=800000 edges, 256 -> 64 (relu) -> 40 (log_softmax)
// Float inputs fp32 or bf16 (device-detected); edges int32 or int64 (detected).
// agg[n] = dinv[n] * ( sum_{s in N(n)} h'[s] + h'[n] ), h' = h*dinv pre-scaled.
// Layer-1 gather is COLUMN-SHARDED: h1 split into two 3.2MB tables (cols 0-31 /
// 32-63); gather blocks pick a shard via blockIdx&1 so, under the %8 round-robin
// block->XCD heuristic, each XCD's 4MB L2 fully caches one shard. The 64-dim
// g vector is written to gtmp; a small matvec kernel applies W2.

constexpr int NN   = 50000;
constexpr int NNP  = 50048;                 // padded row count (zero rows >= NN)
constexpr int ZR   = 50000;                 // zero-row index for padding lanes
constexpr int NE   = 800000;
constexpr int FEAT = 256;
constexpr int HID  = 64;
constexpr int OUTD = 40;
constexpr int NC   = (NN + 255) / 256;     // 196 scan chunks
constexpr int FCH  = 2048;                  // fill: edges per chunk
constexpr int NCH  = (NE + FCH - 1) / FCH;  // 391 chunks
constexpr int NG1  = (NN + 31) / 32;        // 1563 node-groups for sharded gather

typedef short bf16x8 __attribute__((ext_vector_type(8)));
typedef float f32x4  __attribute__((ext_vector_type(4)));

__device__ __forceinline__ float b2f(__hip_bfloat16 v) { return __bfloat162float(v); }
__device__ __forceinline__ float bflo(unsigned u) { return __uint_as_float(u << 16); }
__device__ __forceinline__ float bfhi(unsigned u) { return __uint_as_float(u & 0xffff0000u); }
__device__ __forceinline__ float us2f(unsigned short u) { return __uint_as_float((unsigned)u << 16); }
__device__ __forceinline__ unsigned short f2bu(float f) {
    __hip_bfloat16 h = __float2bfloat16(f);
    return *(unsigned short*)&h;
}
__device__ __forceinline__ unsigned pack2bf(float a, float b) {
    return (unsigned)f2bu(a) | ((unsigned)f2bu(b) << 16);
}
__device__ __forceinline__ float loadF(const void* p, int i, bool f32) {
    return f32 ? ((const float*)p)[i] : b2f(((const __hip_bfloat16*)p)[i]);
}
__device__ __forceinline__ int loadE(const int* ei, int e, int row, bool i64) {
    long long idx = (long long)row * NE + e;
    return i64 ? ei[2 * idx] : ei[idx];
}
__device__ __forceinline__ bf16x8 pack8(float4 a, float4 b) {
    bf16x8 r;
    r[0] = (short)f2bu(a.x); r[1] = (short)f2bu(a.y);
    r[2] = (short)f2bu(a.z); r[3] = (short)f2bu(a.w);
    r[4] = (short)f2bu(b.x); r[5] = (short)f2bu(b.y);
    r[6] = (short)f2bu(b.z); r[7] = (short)f2bu(b.w);
    return r;
}

// ---- zero + dtype detection + h2 pad-row zero ------------------------------
__global__ __launch_bounds__(256) void k_zero(const unsigned* __restrict__ xw,
                                              const int* __restrict__ ew,
                                              int* flags, int* cnt,
                                              unsigned* __restrict__ h2pad) {
    int i = blockIdx.x * 256 + threadIdx.x;
    if (i < NN) cnt[i] = 0;
    if (blockIdx.x == 0 && threadIdx.x < 20) h2pad[threadIdx.x] = 0;  // h2 zero row
    if (blockIdx.x == 0 && threadIdx.x == 0) {
        int outliers = 0;
        for (int k = 0; k < 256; k++) {
            int e = (xw[k] >> 7) & 0xFF;   // exponent of low bf16 half
            if (e < 100 || e > 140) outliers++;
        }
        flags[0] = (outliers > 64) ? 1 : 0;
        int nz = 0;
        for (int k = 1; k < 64; k += 2)
            if (ew[k] != 0) nz++;
        flags[1] = (nz == 0) ? 1 : 0;
    }
}

// ---- CSR build -------------------------------------------------------------
__global__ __launch_bounds__(256) void k_hist(const int* __restrict__ ei,
                                              const int* __restrict__ flags,
                                              int* cnt, int* __restrict__ rank) {
    const bool i64 = flags[1] != 0;
    int e = blockIdx.x * 256 + threadIdx.x;
    if (e < NE) rank[e] = atomicAdd(&cnt[loadE(ei, e, 1, i64)], 1);
}
__global__ __launch_bounds__(256) void k_scan1(const int* __restrict__ cnt,
                                               int* row_start, int* partial, float* dinv) {
    __shared__ int s[256];
    int t = threadIdx.x, i = blockIdx.x * 256 + t;
    int v = (i < NN) ? cnt[i] : 0;
    if (i < NN) dinv[i] = rsqrtf(1.0f + (float)v);   // +1 self loop
    s[t] = v;
    __syncthreads();
    for (int off = 1; off < 256; off <<= 1) {
        int tmp = (t >= off) ? s[t - off] : 0;
        __syncthreads();
        s[t] += tmp;
        __syncthreads();
    }
    if (i < NN) row_start[i] = s[t] - v;
    if (t == 255) partial[blockIdx.x] = s[255];
}
__global__ __launch_bounds__(256) void k_scan2p(const int* __restrict__ partial, int* pp) {
    __shared__ int s[256];
    int t = threadIdx.x;
    int v = (t < NC) ? partial[t] : 0;
    s[t] = v;
    __syncthreads();
    for (int off = 1; off < 256; off <<= 1) {
        int tmp = (t >= off) ? s[t - off] : 0;
        __syncthreads();
        s[t] += tmp;
        __syncthreads();
    }
    pp[t] = s[t] - v;
}
__global__ __launch_bounds__(256) void k_fill(const int* __restrict__ ei,
                                              const int* __restrict__ flags,
                                              const int* __restrict__ row_start,
                                              const int* __restrict__ pp,
                                              const int* __restrict__ rank,
                                              unsigned short* __restrict__ csr16) {
    const bool i64 = flags[1] != 0;
    const int cls = blockIdx.x & 7;
    const int e0 = (blockIdx.x >> 3) * FCH;
#pragma unroll
    for (int k = 0; k < FCH / 256; k++) {
        int e = e0 + k * 256 + threadIdx.x;
        if (e < NE) {
            int d = loadE(ei, e, 1, i64);
            if (d / 6250 == cls) {
                int s = loadE(ei, e, 0, i64);
                csr16[row_start[d] + pp[d >> 8] + rank[e]] = (unsigned short)s;
            }
        }
    }
}

// ---- layer 1 GEMM (MFMA): h1' = (x @ W1) * dinv[row], split column shards --
__global__ __launch_bounds__(256) void k_gemm1(const void* __restrict__ xb,
                                               const void* __restrict__ W1,
                                               const float* __restrict__ dinv,
                                               const int* __restrict__ flags,
                                               unsigned short* __restrict__ h1a,
                                               unsigned short* __restrict__ h1b) {
    __shared__ __align__(16) unsigned short wt16[64 * 264];
    const bool f32 = flags[0] != 0;
    const int t = threadIdx.x;
    if (f32) {
        const float* wf = (const float*)W1;
        for (int i = t * 4; i < FEAT * HID; i += 1024) {
            float4 w = *(const float4*)(wf + i);
            int k = i >> 6, n0 = i & 63;
            wt16[(n0 + 0) * 264 + k] = f2bu(w.x);
            wt16[(n0 + 1) * 264 + k] = f2bu(w.y);
            wt16[(n0 + 2) * 264 + k] = f2bu(w.z);
            wt16[(n0 + 3) * 264 + k] = f2bu(w.w);
        }
    } else {
        const unsigned short* wu = (const unsigned short*)W1;
        for (int i = t * 4; i < FEAT * HID; i += 1024) {
            ushort4 w = *(const ushort4*)(wu + i);
            int k = i >> 6, n0 = i & 63;
            wt16[(n0 + 0) * 264 + k] = w.x;
            wt16[(n0 + 1) * 264 + k] = w.y;
            wt16[(n0 + 2) * 264 + k] = w.z;
            wt16[(n0 + 3) * 264 + k] = w.w;
        }
    }
    const int wv = t >> 6, lane = t & 63, l15 = lane & 15, quad = lane >> 4;
    const int gr = blockIdx.x * 64 + wv * 16 + l15;
    const bool rowok = gr < NN;
    f32x4 acc[4];
#pragma unroll
    for (int nt = 0; nt < 4; nt++) acc[nt] = (f32x4){0.f, 0.f, 0.f, 0.f};
    __syncthreads();

    if (f32) {
        const float* xr = (const float*)xb + (size_t)gr * FEAT + quad * 8;
        float4 z4 = make_float4(0, 0, 0, 0);
        float4 c0 = rowok ? *(const float4*)xr : z4;
        float4 c1 = rowok ? *(const float4*)(xr + 4) : z4;
#pragma unroll
        for (int ks = 0; ks < 8; ks++) {
            float4 n0 = z4, n1 = z4;
            if (ks < 7 && rowok) {
                n0 = *(const float4*)(xr + (ks + 1) * 32);
                n1 = *(const float4*)(xr + (ks + 1) * 32 + 4);
            }
            bf16x8 a = pack8(c0, c1);
            const unsigned short* wk = wt16 + ks * 32 + quad * 8;
#pragma unroll
            for (int nt = 0; nt < 4; nt++) {
                bf16x8 b = *(const bf16x8*)(wk + (size_t)(nt * 16 + l15) * 264);
                acc[nt] = __builtin_amdgcn_mfma_f32_16x16x32_bf16(a, b, acc[nt], 0, 0, 0);
            }
            c0 = n0; c1 = n1;
        }
    } else {
        const unsigned short* xr = (const unsigned short*)xb + (size_t)gr * FEAT + quad * 8;
        bf16x8 zz = (bf16x8){0, 0, 0, 0, 0, 0, 0, 0};
        bf16x8 cur = rowok ? *(const bf16x8*)xr : zz;
#pragma unroll
        for (int ks = 0; ks < 8; ks++) {
            bf16x8 nxt = zz;
            if (ks < 7 && rowok) nxt = *(const bf16x8*)(xr + (ks + 1) * 32);
            const unsigned short* wk = wt16 + ks * 32 + quad * 8;
#pragma unroll
            for (int nt = 0; nt < 4; nt++) {
                bf16x8 b = *(const bf16x8*)(wk + (size_t)(nt * 16 + l15) * 264);
                acc[nt] = __builtin_amdgcn_mfma_f32_16x16x32_bf16(cur, b, acc[nt], 0, 0, 0);
            }
            cur = nxt;
        }
    }
    const int rbase = blockIdx.x * 64 + wv * 16 + quad * 4;
    float dv[4];
#pragma unroll
    for (int r = 0; r < 4; r++) dv[r] = (rbase + r < NN) ? dinv[rbase + r] : 0.f;
#pragma unroll
    for (int r = 0; r < 4; r++) {
        int grow = rbase + r;   // < NNP always
#pragma unroll
        for (int nt = 0; nt < 2; nt++)
            h1a[(size_t)grow * 32 + nt * 16 + l15] = f2bu(acc[nt][r] * dv[r]);
#pragma unroll
        for (int nt = 2; nt < 4; nt++)
            h1b[(size_t)grow * 32 + (nt - 2) * 16 + l15] = f2bu(acc[nt][r] * dv[r]);
    }
}

// ---- sharded gather layer 1: g-half = relu(dn*sum + b1half) -> gtmp --------
// blockIdx&1 = shard; 8-lane groups (32 nodes/block), uint2 loads, branch-free
// 16-deep batches (zero-row padded). No LDS, no barriers.
__global__ __launch_bounds__(256) void k_gather1s(const uint2* __restrict__ h1av,
                                                  const uint2* __restrict__ h1bv,
                                                  const float* __restrict__ dinv,
                                                  const int* __restrict__ row_start,
                                                  const int* __restrict__ pp,
                                                  const int* __restrict__ cnt,
                                                  const unsigned short* __restrict__ csr16,
                                                  const void* __restrict__ b1,
                                                  const int* __restrict__ flags,
                                                  unsigned short* __restrict__ gtmp) {
    const bool f32 = flags[0] != 0;
    const int half = blockIdx.x & 1;
    const uint2* __restrict__ tab = half ? h1bv : h1av;
    const int t = threadIdx.x;
    const int n = (blockIdx.x >> 1) * 32 + (t >> 3);
    if (n >= NN) return;
    const int l8 = t & 7;
    const float dn = dinv[n];
    uint2 u0 = tab[(size_t)n * 8 + l8];
    float a0 = bflo(u0.x), a1 = bfhi(u0.x), a2 = bflo(u0.y), a3 = bfhi(u0.y);
    float e0 = 0.f, e1 = 0.f, e2 = 0.f, e3 = 0.f;
    const int rs = row_start[n] + pp[n >> 8], c = cnt[n];
    for (int base = 0; base < c; base += 16) {
        int rem = c - base;
        int svA = (l8 < rem)     ? (int)csr16[rs + base + l8]     : ZR;
        int svB = (l8 + 8 < rem) ? (int)csr16[rs + base + 8 + l8] : ZR;
        uint2 b[8], d[8];
#pragma unroll
        for (int j = 0; j < 8; j++) {
            int s = __shfl(svA, j, 8);
            b[j] = tab[(size_t)s * 8 + l8];
        }
#pragma unroll
        for (int j = 0; j < 8; j++) {
            int s = __shfl(svB, j, 8);
            d[j] = tab[(size_t)s * 8 + l8];
        }
#pragma unroll
        for (int j = 0; j < 8; j++) {
            a0 += bflo(b[j].x); a1 += bfhi(b[j].x);
            a2 += bflo(b[j].y); a3 += bfhi(b[j].y);
            e0 += bflo(d[j].x); e1 += bfhi(d[j].x);
            e2 += bflo(d[j].y); e3 += bfhi(d[j].y);
        }
    }
    const int cb = 32 * half + 4 * l8;       // global hidden col base
    float g0 = fmaxf(dn * (a0 + e0) + loadF(b1, cb, f32), 0.f);
    float g1 = fmaxf(dn * (a1 + e1) + loadF(b1, cb + 1, f32), 0.f);
    float g2 = fmaxf(dn * (a2 + e2) + loadF(b1, cb + 2, f32), 0.f);
    float g3 = fmaxf(dn * (a3 + e3) + loadF(b1, cb + 3, f32), 0.f);
    ushort4 pk;
    pk.x = f2bu(g0); pk.y = f2bu(g1); pk.z = f2bu(g2); pk.w = f2bu(g3);
    *(ushort4*)(gtmp + (size_t)n * HID + cb) = pk;
}

// ---- matvec: h2' = dn * (g @ W2)  (gtmp bf16 -> h2 bf16) -------------------
__global__ __launch_bounds__(256) void k_matvec(const unsigned short* __restrict__ gtmp,
                                                const float* __restrict__ dinv,
                                                const void* __restrict__ W2,
                                                const int* __restrict__ flags,
                                                unsigned short* __restrict__ h2u) {
    __shared__ __align__(16) float w2t[OUTD * 68];   // [col][k], stride 68
    __shared__ __align__(16) float gbuf[16 * 68];    // [node][k], stride 68
    __shared__ float dns[16];
    const bool f32 = flags[0] != 0;
    const int t = threadIdx.x;
    const int n0 = blockIdx.x * 16;          // grid = NN/16 = 3125 exact
    for (int i = t; i < HID * OUTD; i += 256) {
        int c = i >> 6, k = i & 63;
        w2t[c * 68 + k] = loadF(W2, (size_t)k * OUTD + c, f32);
    }
    for (int i = t; i < 16 * HID; i += 256) {
        int node = i >> 6, k = i & 63;
        gbuf[node * 68 + k] = us2f(gtmp[(size_t)(n0 + node) * HID + k]);
    }
    if (t < 16) dns[t] = dinv[n0 + t];
    __syncthreads();
    for (int idx = t; idx < 16 * OUTD; idx += 256) {
        int node = idx / OUTD, col = idx % OUTD;
        const float4* gp = (const float4*)(gbuf + node * 68);
        const float4* wp = (const float4*)(w2t + col * 68);
        float o = 0.f;
#pragma unroll 4
        for (int k4 = 0; k4 < 16; k4++) {
            float4 a = gp[k4], b = wp[k4];
            o += a.x * b.x + a.y * b.y + a.z * b.z + a.w * b.w;
        }
        h2u[(size_t)(n0 + node) * OUTD + col] = f2bu(o * dns[node]);
    }
}

// ---- CSR gather layer 2 + bias + log_softmax (branch-free 16-deep) ---------
__global__ __launch_bounds__(256) void k_gather2(const uint2* __restrict__ h2v,
                                                 const float* __restrict__ dinv,
                                                 const int* __restrict__ row_start,
                                                 const int* __restrict__ pp,
                                                 const int* __restrict__ cnt,
                                                 const unsigned short* __restrict__ csr16,
                                                 const void* __restrict__ b2,
                                                 const int* __restrict__ flags,
                                                 void* __restrict__ out) {
    const bool f32 = flags[0] != 0;
    const int t = threadIdx.x;
    const int nl = t >> 4, l16 = t & 15;
    const int n = blockIdx.x * 16 + nl;      // < NN (grid exact)
    const bool act = l16 < 10;               // 10 uint2 per 40-col row
    const float dn = dinv[n];
    const int lclamp = act ? l16 : 9;
    uint2 u0 = h2v[(size_t)n * 10 + lclamp];
    float a0 = bflo(u0.x), a1 = bfhi(u0.x), a2 = bflo(u0.y), a3 = bfhi(u0.y);
    float e0 = 0.f, e1 = 0.f, e2 = 0.f, e3 = 0.f;
    const int rs = row_start[n] + pp[n >> 8], c = cnt[n];
    for (int base = 0; base < c; base += 16) {
        int rem = c - base;
        int sv = (l16 < rem) ? (int)csr16[rs + base + l16] : ZR;
        uint2 b[8], d[8];
#pragma unroll
        for (int j = 0; j < 8; j++) {
            int s = __shfl(sv, j, 16);
            b[j] = h2v[(size_t)s * 10 + lclamp];
        }
#pragma unroll
        for (int j = 0; j < 8; j++) {
            int s = __shfl(sv, j + 8, 16);
            d[j] = h2v[(size_t)s * 10 + lclamp];
        }
#pragma unroll
        for (int j = 0; j < 8; j++) {
            a0 += bflo(b[j].x); a1 += bfhi(b[j].x);
            a2 += bflo(b[j].y); a3 += bfhi(b[j].y);
            e0 += bflo(d[j].x); e1 += bfhi(d[j].x);
            e2 += bflo(d[j].y); e3 += bfhi(d[j].y);
        }
    }
    int cb = 4 * l16;
    float v0 = -3.0e38f, v1 = -3.0e38f, v2 = -3.0e38f, v3 = -3.0e38f;
    if (act) {
        v0 = dn * (a0 + e0) + loadF(b2, cb, f32);
        v1 = dn * (a1 + e1) + loadF(b2, cb + 1, f32);
        v2 = dn * (a2 + e2) + loadF(b2, cb + 2, f32);
        v3 = dn * (a3 + e3) + loadF(b2, cb + 3, f32);
    }
    float mx = fmaxf(fmaxf(v0, v1), fmaxf(v2, v3));
#pragma unroll
    for (int off = 8; off; off >>= 1) mx = fmaxf(mx, __shfl_xor(mx, off, 16));
    float ev = act ? expf(v0 - mx) + expf(v1 - mx) + expf(v2 - mx) + expf(v3 - mx) : 0.f;
#pragma unroll
    for (int off = 8; off; off >>= 1) ev += __shfl_xor(ev, off, 16);
    float lg = logf(ev);
    if (act) {
        float r0 = v0 - mx - lg, r1 = v1 - mx - lg;
        float r2 = v2 - mx - lg, r3 = v3 - mx - lg;
        if (f32) {
            *(float4*)((float*)out + (size_t)n * OUTD + cb) = make_float4(r0, r1, r2, r3);
        } else {
            ((uint2*)out)[(size_t)n * 10 + l16] = make_uint2(pack2bf(r0, r1), pack2bf(r2, r3));
        }
    }
}

extern "C" void kernel_launch(void* const* d_in, const int* in_sizes, int n_in,
                              void* d_out, int out_size, void* d_ws, size_t ws_size,
                              hipStream_t stream) {
    const void* x  = d_in[0];
    const int*  ei = (const int*)d_in[1];
    const void* W1 = d_in[2];
    const void* b1 = d_in[3];
    const void* W2 = d_in[4];
    const void* b2 = d_in[5];

    // ws layout (4-byte words):
    // flags[16] | dinv[50048] | cnt[50048] | row_start[50048] | partial[256] |
    // pp[256] | rank[800000] | csr16 ushort[800000] | h1a bf16 [NNP*32] |
    // h1b bf16 [NNP*32] | gtmp bf16 [NNP*64] | h2 bf16 [NNP*40]   (~22 MB)
    float* ws        = (float*)d_ws;
    int*   flags     = (int*)ws;
    float* dinv      = ws + 16;
    int*   cnt       = (int*)(dinv + 50048);
    int*   row_start = cnt + 50048;
    int*   partial   = row_start + 50048;
    int*   pp        = partial + 256;
    int*   rank      = pp + 256;
    unsigned short* csr16 = (unsigned short*)(rank + NE);
    unsigned short* h1a   = csr16 + NE;
    unsigned short* h1b   = h1a + (size_t)NNP * 32;
    unsigned short* gtmp  = h1b + (size_t)NNP * 32;
    unsigned short* h2u   = gtmp + (size_t)NNP * HID;
    unsigned* h2pad = (unsigned*)(h2u + (size_t)ZR * OUTD);   // 20 dwords

    k_zero  <<<(NN + 255) / 256, 256, 0, stream>>>((const unsigned*)x, ei, flags, cnt, h2pad);
    k_hist  <<<(NE + 255) / 256, 256, 0, stream>>>(ei, flags, cnt, rank);
    k_scan1 <<<NC, 256, 0, stream>>>(cnt, row_start, partial, dinv);
    k_scan2p<<<1, 256, 0, stream>>>(partial, pp);
    k_fill  <<<NCH * 8, 256, 0, stream>>>(ei, flags, row_start, pp, rank, csr16);
    k_gemm1 <<<NNP / 64, 256, 0, stream>>>(x, W1, dinv, flags, h1a, h1b);
    k_gather1s<<<NG1 * 2, 256, 0, stream>>>((const uint2*)h1a, (const uint2*)h1b, dinv,
                                            row_start, pp, cnt, csr16, b1, flags, gtmp);
    k_matvec<<<NN / 16, 256, 0, stream>>>(gtmp, dinv, W2, flags, h2u);
    k_gather2<<<NN / 16, 256, 0, stream>>>((const uint2*)h2u, dinv, row_start, pp, cnt, csr16,
                                           b2, flags, d_out);
}

// Round 12
// 231.112 us; speedup vs baseline: 1.0334x; 1.0334x over previous
//
#include <hip/hip_runtime.h>
#include <hip/hip_bf16.h>

// GCN 2-layer: N=50000 nodes, E=800000 edges, 256 -> 64 (relu) -> 40 (log_softmax)
// Float inputs fp32 or bf16 (device-detected); edges int32 or int64 (detected).
// agg[n] = dinv[n] * ( sum_{s in N(n)} h'[s] + h'[n] ), h' = h*dinv pre-scaled.
// CSR: hist records per-edge rank -> atomic-free fill. FILL AND GEMM1 ARE FUSED
// into one launch (independent work; compute waves hide fill's memory latency).
// Gathers: 4 nodes/wave (16-lane quarters), uint2 loads, branch-free 16-deep
// batches padded with a zero row at index 50000.

constexpr int NN   = 50000;
constexpr int NNP  = 50048;                 // padded row count (zero rows >= NN)
constexpr int ZR   = 50000;                 // zero-row index for padding lanes
constexpr int NE   = 800000;
constexpr int FEAT = 256;
constexpr int HID  = 64;
constexpr int OUTD = 40;
constexpr int NC   = (NN + 255) / 256;     // 196 scan chunks
constexpr int FCH  = 2048;                  // fill: edges per chunk
constexpr int NCH  = (NE + FCH - 1) / FCH;  // 391 chunks
constexpr int GEMB = NNP / 64;              // 782 gemm1 blocks (first in grid)

typedef short bf16x8 __attribute__((ext_vector_type(8)));
typedef float f32x4  __attribute__((ext_vector_type(4)));

__device__ __forceinline__ float b2f(__hip_bfloat16 v) { return __bfloat162float(v); }
__device__ __forceinline__ float bflo(unsigned u) { return __uint_as_float(u << 16); }
__device__ __forceinline__ float bfhi(unsigned u) { return __uint_as_float(u & 0xffff0000u); }
__device__ __forceinline__ unsigned short f2bu(float f) {
    __hip_bfloat16 h = __float2bfloat16(f);
    return *(unsigned short*)&h;
}
__device__ __forceinline__ unsigned pack2bf(float a, float b) {
    return (unsigned)f2bu(a) | ((unsigned)f2bu(b) << 16);
}
__device__ __forceinline__ float loadF(const void* p, int i, bool f32) {
    return f32 ? ((const float*)p)[i] : b2f(((const __hip_bfloat16*)p)[i]);
}
__device__ __forceinline__ int loadE(const int* ei, int e, int row, bool i64) {
    long long idx = (long long)row * NE + e;
    return i64 ? ei[2 * idx] : ei[idx];
}
__device__ __forceinline__ bf16x8 pack8(float4 a, float4 b) {
    bf16x8 r;
    r[0] = (short)f2bu(a.x); r[1] = (short)f2bu(a.y);
    r[2] = (short)f2bu(a.z); r[3] = (short)f2bu(a.w);
    r[4] = (short)f2bu(b.x); r[5] = (short)f2bu(b.y);
    r[6] = (short)f2bu(b.z); r[7] = (short)f2bu(b.w);
    return r;
}

// ---- zero + dtype detection + h2 pad-row zero ------------------------------
__global__ __launch_bounds__(256) void k_zero(const unsigned* __restrict__ xw,
                                              const int* __restrict__ ew,
                                              int* flags, int* cnt,
                                              unsigned* __restrict__ h2pad) {
    int i = blockIdx.x * 256 + threadIdx.x;
    if (i < NN) cnt[i] = 0;
    if (blockIdx.x == 0 && threadIdx.x < 20) h2pad[threadIdx.x] = 0;  // h2 zero row
    if (blockIdx.x == 0 && threadIdx.x == 0) {
        int outliers = 0;
        for (int k = 0; k < 256; k++) {
            int e = (xw[k] >> 7) & 0xFF;   // exponent of low bf16 half
            if (e < 100 || e > 140) outliers++;
        }
        flags[0] = (outliers > 64) ? 1 : 0;
        int nz = 0;
        for (int k = 1; k < 64; k += 2)
            if (ew[k] != 0) nz++;
        flags[1] = (nz == 0) ? 1 : 0;
    }
}

// ---- CSR build -------------------------------------------------------------
__global__ __launch_bounds__(256) void k_hist(const int* __restrict__ ei,
                                              const int* __restrict__ flags,
                                              int* cnt, int* __restrict__ rank) {
    const bool i64 = flags[1] != 0;
    int e = blockIdx.x * 256 + threadIdx.x;
    if (e < NE) rank[e] = atomicAdd(&cnt[loadE(ei, e, 1, i64)], 1);
}
__global__ __launch_bounds__(256) void k_scan1(const int* __restrict__ cnt,
                                               int* row_start, int* partial, float* dinv) {
    __shared__ int s[256];
    int t = threadIdx.x, i = blockIdx.x * 256 + t;
    int v = (i < NN) ? cnt[i] : 0;
    if (i < NN) dinv[i] = rsqrtf(1.0f + (float)v);   // +1 self loop
    s[t] = v;
    __syncthreads();
    for (int off = 1; off < 256; off <<= 1) {
        int tmp = (t >= off) ? s[t - off] : 0;
        __syncthreads();
        s[t] += tmp;
        __syncthreads();
    }
    if (i < NN) row_start[i] = s[t] - v;       // exclusive within chunk
    if (t == 255) partial[blockIdx.x] = s[255];
}
__global__ __launch_bounds__(256) void k_scan2p(const int* __restrict__ partial, int* pp) {
    __shared__ int s[256];
    int t = threadIdx.x;
    int v = (t < NC) ? partial[t] : 0;
    s[t] = v;
    __syncthreads();
    for (int off = 1; off < 256; off <<= 1) {
        int tmp = (t >= off) ? s[t - off] : 0;
        __syncthreads();
        s[t] += tmp;
        __syncthreads();
    }
    pp[t] = s[t] - v;
}

// ---- FUSED fill + gemm1 ----------------------------------------------------
// Blocks [0, GEMB): MFMA gemm1  h1' = (x @ W1) * dinv[row]  (64 rows/block).
// Blocks [GEMB, GEMB+NCH*8): atomic-free CSR fill (class-partitioned).
// Independent work items; co-residency lets gemm1's compute hide fill's
// memory latency instead of running the two kernels back-to-back.
__global__ __launch_bounds__(256) void k_fillgemm1(const int* __restrict__ ei,
                                                   const int* __restrict__ flags,
                                                   const int* __restrict__ row_start,
                                                   const int* __restrict__ pp,
                                                   const int* __restrict__ rank,
                                                   unsigned short* __restrict__ csr16,
                                                   const void* __restrict__ xb,
                                                   const void* __restrict__ W1,
                                                   const float* __restrict__ dinv,
                                                   unsigned short* __restrict__ h1u) {
    __shared__ __align__(16) unsigned short wt16[64 * 264];
    const int t = threadIdx.x;
    if (blockIdx.x >= GEMB) {
        // ---------------- fill body ----------------
        const bool i64 = flags[1] != 0;
        const int fb = blockIdx.x - GEMB;
        const int cls = fb & 7;
        const int e0 = (fb >> 3) * FCH;
#pragma unroll
        for (int k = 0; k < FCH / 256; k++) {
            int e = e0 + k * 256 + t;
            if (e < NE) {
                int d = loadE(ei, e, 1, i64);
                if (d / 6250 == cls) {
                    int s = loadE(ei, e, 0, i64);
                    csr16[row_start[d] + pp[d >> 8] + rank[e]] = (unsigned short)s;
                }
            }
        }
        return;
    }
    // ---------------- gemm1 body ----------------
    const bool f32 = flags[0] != 0;
    if (f32) {
        const float* wf = (const float*)W1;
        for (int i = t * 4; i < FEAT * HID; i += 1024) {
            float4 w = *(const float4*)(wf + i);
            int k = i >> 6, n0 = i & 63;
            wt16[(n0 + 0) * 264 + k] = f2bu(w.x);
            wt16[(n0 + 1) * 264 + k] = f2bu(w.y);
            wt16[(n0 + 2) * 264 + k] = f2bu(w.z);
            wt16[(n0 + 3) * 264 + k] = f2bu(w.w);
        }
    } else {
        const unsigned short* wu = (const unsigned short*)W1;
        for (int i = t * 4; i < FEAT * HID; i += 1024) {
            ushort4 w = *(const ushort4*)(wu + i);
            int k = i >> 6, n0 = i & 63;
            wt16[(n0 + 0) * 264 + k] = w.x;
            wt16[(n0 + 1) * 264 + k] = w.y;
            wt16[(n0 + 2) * 264 + k] = w.z;
            wt16[(n0 + 3) * 264 + k] = w.w;
        }
    }
    const int wv = t >> 6, lane = t & 63, l15 = lane & 15, quad = lane >> 4;
    const int gr = blockIdx.x * 64 + wv * 16 + l15;
    const bool rowok = gr < NN;
    f32x4 acc[4];
#pragma unroll
    for (int nt = 0; nt < 4; nt++) acc[nt] = (f32x4){0.f, 0.f, 0.f, 0.f};
    __syncthreads();

    if (f32) {
        const float* xr = (const float*)xb + (size_t)gr * FEAT + quad * 8;
        float4 z4 = make_float4(0, 0, 0, 0);
        float4 c0 = rowok ? *(const float4*)xr : z4;
        float4 c1 = rowok ? *(const float4*)(xr + 4) : z4;
#pragma unroll
        for (int ks = 0; ks < 8; ks++) {
            float4 n0 = z4, n1 = z4;
            if (ks < 7 && rowok) {
                n0 = *(const float4*)(xr + (ks + 1) * 32);
                n1 = *(const float4*)(xr + (ks + 1) * 32 + 4);
            }
            bf16x8 a = pack8(c0, c1);
            const unsigned short* wk = wt16 + ks * 32 + quad * 8;
#pragma unroll
            for (int nt = 0; nt < 4; nt++) {
                bf16x8 b = *(const bf16x8*)(wk + (size_t)(nt * 16 + l15) * 264);
                acc[nt] = __builtin_amdgcn_mfma_f32_16x16x32_bf16(a, b, acc[nt], 0, 0, 0);
            }
            c0 = n0; c1 = n1;
        }
    } else {
        const unsigned short* xr = (const unsigned short*)xb + (size_t)gr * FEAT + quad * 8;
        bf16x8 zz = (bf16x8){0, 0, 0, 0, 0, 0, 0, 0};
        bf16x8 cur = rowok ? *(const bf16x8*)xr : zz;
#pragma unroll
        for (int ks = 0; ks < 8; ks++) {
            bf16x8 nxt = zz;
            if (ks < 7 && rowok) nxt = *(const bf16x8*)(xr + (ks + 1) * 32);
            const unsigned short* wk = wt16 + ks * 32 + quad * 8;
#pragma unroll
            for (int nt = 0; nt < 4; nt++) {
                bf16x8 b = *(const bf16x8*)(wk + (size_t)(nt * 16 + l15) * 264);
                acc[nt] = __builtin_amdgcn_mfma_f32_16x16x32_bf16(cur, b, acc[nt], 0, 0, 0);
            }
            cur = nxt;
        }
    }
    const int rbase = blockIdx.x * 64 + wv * 16 + quad * 4;
    float dv[4];
#pragma unroll
    for (int r = 0; r < 4; r++) dv[r] = (rbase + r < NN) ? dinv[rbase + r] : 0.f;
#pragma unroll
    for (int r = 0; r < 4; r++) {
        int grow = rbase + r;   // < NNP always
#pragma unroll
        for (int nt = 0; nt < 4; nt++)
            h1u[(size_t)grow * HID + nt * 16 + l15] = f2bu(acc[nt][r] * dv[r]);
    }
}

// ---- fused: s = sum h1'[{n}uN(n)] ; g = relu(dn*s + b1) ; h2' = dn*(g@W2) --
// 4 nodes/wave, uint2/lane, branch-free 16-deep batches (zero-row padded).
__global__ __launch_bounds__(256) void k_gather1f(const uint2* __restrict__ h1v,
                                                  const float* __restrict__ dinv,
                                                  const int* __restrict__ row_start,
                                                  const int* __restrict__ pp,
                                                  const int* __restrict__ cnt,
                                                  const unsigned short* __restrict__ csr16,
                                                  const void* __restrict__ W2,
                                                  const void* __restrict__ b1,
                                                  const int* __restrict__ flags,
                                                  unsigned short* __restrict__ h2u) {
    __shared__ __align__(16) float w2t[OUTD * 68];   // [col][k], stride 68
    __shared__ __align__(16) float gbuf[16 * 68];    // [node][k], stride 68
    __shared__ float dns[16];
    const bool f32 = flags[0] != 0;
    const int t = threadIdx.x;
    for (int i = t; i < HID * OUTD; i += 256) {
        int c = i >> 6, k = i & 63;
        w2t[c * 68 + k] = loadF(W2, (size_t)k * OUTD + c, f32);
    }
    const int nl = t >> 4, l16 = t & 15;
    const int n = blockIdx.x * 16 + nl;      // < NN (grid exact)
    const float dn = dinv[n];
    uint2 u0 = h1v[(size_t)n * 16 + l16];
    float a0 = bflo(u0.x), a1 = bfhi(u0.x), a2 = bflo(u0.y), a3 = bfhi(u0.y);
    float e0 = 0.f, e1 = 0.f, e2 = 0.f, e3 = 0.f;
    const int rs = row_start[n] + pp[n >> 8], c = cnt[n];
    for (int base = 0; base < c; base += 16) {
        int rem = c - base;
        int sv = (l16 < rem) ? (int)csr16[rs + base + l16] : ZR;
        uint2 b[8], d[8];
#pragma unroll
        for (int j = 0; j < 8; j++) {
            int s = __shfl(sv, j, 16);
            b[j] = h1v[(size_t)s * 16 + l16];
        }
#pragma unroll
        for (int j = 0; j < 8; j++) {
            int s = __shfl(sv, j + 8, 16);
            d[j] = h1v[(size_t)s * 16 + l16];
        }
#pragma unroll
        for (int j = 0; j < 8; j++) {
            a0 += bflo(b[j].x); a1 += bfhi(b[j].x);
            a2 += bflo(b[j].y); a3 += bfhi(b[j].y);
            e0 += bflo(d[j].x); e1 += bfhi(d[j].x);
            e2 += bflo(d[j].y); e3 += bfhi(d[j].y);
        }
    }
    int cb = 4 * l16;
    float g0 = fmaxf(dn * (a0 + e0) + loadF(b1, cb, f32), 0.f);
    float g1 = fmaxf(dn * (a1 + e1) + loadF(b1, cb + 1, f32), 0.f);
    float g2 = fmaxf(dn * (a2 + e2) + loadF(b1, cb + 2, f32), 0.f);
    float g3 = fmaxf(dn * (a3 + e3) + loadF(b1, cb + 3, f32), 0.f);
    *(float4*)(gbuf + nl * 68 + cb) = make_float4(g0, g1, g2, g3);
    if (l16 == 0) dns[nl] = dn;
    __syncthreads();
    for (int idx = t; idx < 16 * OUTD; idx += 256) {
        int node = idx / OUTD, col = idx % OUTD;
        const float4* gp = (const float4*)(gbuf + node * 68);
        const float4* wp = (const float4*)(w2t + col * 68);
        float o = 0.f;
#pragma unroll 4
        for (int k4 = 0; k4 < 16; k4++) {
            float4 a = gp[k4], b = wp[k4];
            o += a.x * b.x + a.y * b.y + a.z * b.z + a.w * b.w;
        }
        h2u[(size_t)(blockIdx.x * 16 + node) * OUTD + col] = f2bu(o * dns[node]);
    }
}

// ---- CSR gather layer 2 + bias + log_softmax (branch-free 16-deep) ---------
__global__ __launch_bounds__(256) void k_gather2(const uint2* __restrict__ h2v,
                                                 const float* __restrict__ dinv,
                                                 const int* __restrict__ row_start,
                                                 const int* __restrict__ pp,
                                                 const int* __restrict__ cnt,
                                                 const unsigned short* __restrict__ csr16,
                                                 const void* __restrict__ b2,
                                                 const int* __restrict__ flags,
                                                 void* __restrict__ out) {
    const bool f32 = flags[0] != 0;
    const int t = threadIdx.x;
    const int nl = t >> 4, l16 = t & 15;
    const int n = blockIdx.x * 16 + nl;      // < NN (grid exact)
    const bool act = l16 < 10;               // 10 uint2 per 40-col row
    const float dn = dinv[n];
    const int lclamp = act ? l16 : 9;
    uint2 u0 = h2v[(size_t)n * 10 + lclamp];
    float a0 = bflo(u0.x), a1 = bfhi(u0.x), a2 = bflo(u0.y), a3 = bfhi(u0.y);
    float e0 = 0.f, e1 = 0.f, e2 = 0.f, e3 = 0.f;
    const int rs = row_start[n] + pp[n >> 8], c = cnt[n];
    for (int base = 0; base < c; base += 16) {
        int rem = c - base;
        int sv = (l16 < rem) ? (int)csr16[rs + base + l16] : ZR;
        uint2 b[8], d[8];
#pragma unroll
        for (int j = 0; j < 8; j++) {
            int s = __shfl(sv, j, 16);
            b[j] = h2v[(size_t)s * 10 + lclamp];
        }
#pragma unroll
        for (int j = 0; j < 8; j++) {
            int s = __shfl(sv, j + 8, 16);
            d[j] = h2v[(size_t)s * 10 + lclamp];
        }
#pragma unroll
        for (int j = 0; j < 8; j++) {
            a0 += bflo(b[j].x); a1 += bfhi(b[j].x);
            a2 += bflo(b[j].y); a3 += bfhi(b[j].y);
            e0 += bflo(d[j].x); e1 += bfhi(d[j].x);
            e2 += bflo(d[j].y); e3 += bfhi(d[j].y);
        }
    }
    int cb = 4 * l16;
    float v0 = -3.0e38f, v1 = -3.0e38f, v2 = -3.0e38f, v3 = -3.0e38f;
    if (act) {
        v0 = dn * (a0 + e0) + loadF(b2, cb, f32);
        v1 = dn * (a1 + e1) + loadF(b2, cb + 1, f32);
        v2 = dn * (a2 + e2) + loadF(b2, cb + 2, f32);
        v3 = dn * (a3 + e3) + loadF(b2, cb + 3, f32);
    }
    float mx = fmaxf(fmaxf(v0, v1), fmaxf(v2, v3));
#pragma unroll
    for (int off = 8; off; off >>= 1) mx = fmaxf(mx, __shfl_xor(mx, off, 16));
    float ev = act ? expf(v0 - mx) + expf(v1 - mx) + expf(v2 - mx) + expf(v3 - mx) : 0.f;
#pragma unroll
    for (int off = 8; off; off >>= 1) ev += __shfl_xor(ev, off, 16);
    float lg = logf(ev);
    if (act) {
        float r0 = v0 - mx - lg, r1 = v1 - mx - lg;
        float r2 = v2 - mx - lg, r3 = v3 - mx - lg;
        if (f32) {
            *(float4*)((float*)out + (size_t)n * OUTD + cb) = make_float4(r0, r1, r2, r3);
        } else {
            ((uint2*)out)[(size_t)n * 10 + l16] = make_uint2(pack2bf(r0, r1), pack2bf(r2, r3));
        }
    }
}

extern "C" void kernel_launch(void* const* d_in, const int* in_sizes, int n_in,
                              void* d_out, int out_size, void* d_ws, size_t ws_size,
                              hipStream_t stream) {
    const void* x  = d_in[0];
    const int*  ei = (const int*)d_in[1];
    const void* W1 = d_in[2];
    const void* b1 = d_in[3];
    const void* W2 = d_in[4];
    const void* b2 = d_in[5];

    // ws layout (4-byte words):
    // flags[16] | dinv[50048] | cnt[50048] | row_start[50048] | partial[256] |
    // pp[256] | rank[800000] | csr16 ushort[800000] | h1' bf16 [NNP*64] |
    // h2' bf16 [NNP*40]   (~15.8 MB)
    float* ws        = (float*)d_ws;
    int*   flags     = (int*)ws;
    float* dinv      = ws + 16;
    int*   cnt       = (int*)(dinv + 50048);
    int*   row_start = cnt + 50048;
    int*   partial   = row_start + 50048;
    int*   pp        = partial + 256;
    int*   rank      = pp + 256;
    unsigned short* csr16 = (unsigned short*)(rank + NE);
    unsigned short* h1u   = csr16 + NE;
    unsigned short* h2u   = h1u + (size_t)NNP * HID;
    unsigned* h2pad = (unsigned*)(h2u + (size_t)ZR * OUTD);   // 20 dwords

    k_zero  <<<(NN + 255) / 256, 256, 0, stream>>>((const unsigned*)x, ei, flags, cnt, h2pad);
    k_hist  <<<(NE + 255) / 256, 256, 0, stream>>>(ei, flags, cnt, rank);
    k_scan1 <<<NC, 256, 0, stream>>>(cnt, row_start, partial, dinv);
    k_scan2p<<<1, 256, 0, stream>>>(partial, pp);
    k_fillgemm1<<<GEMB + NCH * 8, 256, 0, stream>>>(ei, flags, row_start, pp, rank, csr16,
                                                    x, W1, dinv, h1u);
    k_gather1f<<<NN / 16, 256, 0, stream>>>((const uint2*)h1u, dinv, row_start, pp, cnt, csr16,
                                            W2, b1, flags, h2u);
    k_gather2<<<NN / 16, 256, 0, stream>>>((const uint2*)h2u, dinv, row_start, pp, cnt, csr16,
                                           b2, flags, d_out);
}